// Round 3
// baseline (1205.480 us; speedup 1.0000x reference)
//
#include <hip/hip_runtime.h>
#include <cmath>
#include <complex>
#include <vector>
#include <algorithm>

#define DEVFN __device__ __forceinline__

typedef short short8 __attribute__((ext_vector_type(8)));
typedef float f32x4  __attribute__((ext_vector_type(4)));

namespace {

constexpr int NNODE  = 50000;
constexpr int TILE_Z = 16;
constexpr int NBLOCK = NNODE / TILE_Z;   // 3125, exact
static_assert(NBLOCK * TILE_Z == NNODE, "tile");

// INSTR = [(0,0,0),(0,1,1),(0,2,2),(1,0,1),(1,1,0),(1,1,1),(1,1,2),(1,2,1),
//          (1,2,2),(2,0,2),(2,1,1),(2,1,2),(2,2,0),(2,2,1),(2,2,2)]
constexpr int I_L1[15] = {0,0,0,1,1,1,1,1,1,2,2,2,2,2,2};
constexpr int I_L2[15] = {0,1,2,0,1,1,1,2,2,0,1,1,2,2,2};
constexpr int I_LO[15] = {0,1,2,1,0,1,2,1,2,2,1,2,0,1,2};
// flattened w3j offsets; sizes (2l1+1)(2l2+1)(2lo+1) -> total 615
constexpr int W3OFF[15] = {0,1,10,35,44,53,80,125,170,245,270,315,390,415,490};
constexpr int LOFF[3] = {0,1,4};     // basis-dim offset of each l block

struct TPParams { float w3j[615]; };
struct AlphaArg { float a[15]; };

// ---------------- host: e3nn-convention wigner 3j (proven) ------------------
double ffact(int n){ double r=1.0; for(int i=2;i<=n;++i) r*=i; return r; }

double su2cg(int j1,int m1,int j2,int m2,int j3,int m3){
  if(m3 != m1+m2) return 0.0;
  int vmin = std::max(std::max(-j1+j2+m3, -j1+m1), 0);
  int vmax = std::min(std::min(j2+j3+m1, j3-j1+j2), j3+m3);
  double C = std::sqrt((2.0*j3+1.0)*ffact(j3+j1-j2)*ffact(j3-j1+j2)*ffact(j1+j2-j3)
             /ffact(j1+j2+j3+1)
             *ffact(j3+m3)*ffact(j3-m3)
             /(ffact(j1-m1)*ffact(j1+m1)*ffact(j2-m2)*ffact(j2+m2)));
  double S = 0.0;
  for(int v=vmin; v<=vmax; ++v){
    double t = ffact(j2+j3+m1-v)*ffact(j1-m1+v)
             /(ffact(v)*ffact(j3-j1+j2-v)*ffact(j3+m3-v)*ffact(v+j1-j2-m3));
    S += ((v+j2+m2)&1) ? -t : t;
  }
  return C*S;
}

void cbasis(int l, std::complex<double>* q){
  int n = 2*l+1;
  for(int i=0;i<n*n;++i) q[i] = std::complex<double>(0.0,0.0);
  const double is2 = 1.0/std::sqrt(2.0);
  for(int m=-l; m<0; ++m){
    q[(l+m)*n + (l-m)] = std::complex<double>(is2, 0.0);
    q[(l+m)*n + (l+m)] = std::complex<double>(0.0, -is2);
  }
  q[l*n+l] = std::complex<double>(1.0, 0.0);
  for(int m=1; m<=l; ++m){
    double s = (m&1) ? -1.0 : 1.0;
    q[(l+m)*n + (l+m)] = std::complex<double>(s*is2, 0.0);
    q[(l+m)*n + (l-m)] = std::complex<double>(0.0, s*is2);
  }
  std::complex<double> ph;
  switch(l&3){ case 0: ph = std::complex<double>(1,0);  break;
               case 1: ph = std::complex<double>(0,-1); break;
               case 2: ph = std::complex<double>(-1,0); break;
               default: ph = std::complex<double>(0,1);  break; }
  for(int i=0;i<n*n;++i) q[i] *= ph;
}

void wigner3j_tab(int l1,int l2,int l3, float* dst){
  int n1=2*l1+1, n2=2*l2+1, n3=2*l3+1;
  std::vector<double> C(n1*n2*n3);
  for(int i=0;i<n1;++i) for(int k=0;k<n2;++k) for(int n=0;n<n3;++n)
    C[(i*n2+k)*n3+n] = su2cg(l1,i-l1, l2,k-l2, l3,n-l3);
  std::vector<std::complex<double>> Q1(n1*n1), Q2(n2*n2), Q3(n3*n3);
  cbasis(l1,Q1.data()); cbasis(l2,Q2.data()); cbasis(l3,Q3.data());
  std::vector<double> R(n1*n2*n3, 0.0);
  for(int j=0;j<n1;++j) for(int l=0;l<n2;++l) for(int m=0;m<n3;++m){
    std::complex<double> s(0,0);
    for(int i=0;i<n1;++i) for(int k=0;k<n2;++k) for(int n=0;n<n3;++n)
      s += Q1[i*n1+j]*Q2[k*n2+l]*std::conj(Q3[n*n3+m])*C[(i*n2+k)*n3+n];
    R[(j*n2+l)*n3+m] = s.real();
  }
  double nrm=0; for(double v:R) nrm += v*v; nrm = std::sqrt(nrm);
  for(int t=0;t<n1*n2*n3;++t) dst[t] = (float)(R[t]/nrm);
}

void fill_params(TPParams& P, AlphaArg& A){
  for(int ins=0; ins<15; ++ins)
    wigner3j_tab(I_L1[ins], I_L2[ins], I_LO[ins], P.w3j + W3OFF[ins]);
  int cnt[3] = {0,0,0};
  for(int ins=0; ins<15; ++ins) cnt[I_LO[ins]]++;      // {3,6,6}
  for(int ins=0; ins<15; ++ins){
    int lo = I_LO[ins];
    A.a[ins] = (float)std::sqrt((2.0*lo+1.0)/(128.0*cnt[lo]));
  }
}

} // namespace

// ---------------- device helpers -------------------------------------------
DEVFN unsigned f2bf(float f){                       // fp32 -> bf16 bits (RNE)
  unsigned u = __float_as_uint(f);
  return (u + 0x7fffu + ((u>>16)&1u)) >> 16;
}
DEVFN unsigned pkbf(float a, float b){ return f2bf(a) | (f2bf(b)<<16); }

template<typename T, typename F>
DEVFN T bc(F f){ static_assert(sizeof(T)==sizeof(F), "size"); T t; __builtin_memcpy(&t,&f,sizeof(T)); return t; }

// ---------------- prep: weights -> bf16, alpha folded, swizzled WT ----------
// dst layout (per path p): row w (0..127), 16 groups of 8 consecutive u;
// logical u-group (u>>3) stored at position (u>>3) ^ (w&15)  [bank swizzle]
__global__ __launch_bounds__(256)
void prep_kernel(const float* __restrict__ w, unsigned short* __restrict__ ws,
                 AlphaArg al)
{
  int t = blockIdx.x*256 + threadIdx.x;          // < 15*16384 = 245760
  int p = t >> 14, rem = t & 16383, u = rem >> 7, col = rem & 127;
  float v = w[t] * al.a[p];
  int gs = (u>>3) ^ (col & 15);
  ws[(p<<14) + (col<<7) + (gs<<3) + (u&7)] = (unsigned short)f2bf(v);
}

// ---------------- phase A: xx_p[k][z][u] (bf16, swizzled) -------------------
template<int INS>
DEVFN void path_phaseA(const TPParams& P, const unsigned x1p[9][4],
                       const float x2r[9], uint4* sxxU4, int z, int ug)
{
  constexpr int L1 = I_L1[INS], L2 = I_L2[INS], LO = I_LO[INS];
  constexpr int N1 = 2*L1+1, N2 = 2*L2+1, NO = 2*LO+1;
  constexpr int O1 = LOFF[L1], O2 = LOFF[L2], W3 = W3OFF[INS];

  float cc[NO][N1];
  #pragma unroll
  for(int k=0;k<NO;++k){
    #pragma unroll
    for(int i=0;i<N1;++i){
      float s = 0.f;
      #pragma unroll
      for(int j=0;j<N2;++j)
        s += P.w3j[W3 + (i*N2+j)*NO + k] * x2r[O2 + j];
      cc[k][i] = s;
    }
  }
  float a8[NO][8];
  #pragma unroll
  for(int k=0;k<NO;++k){
    #pragma unroll
    for(int e=0;e<8;++e) a8[k][e]=0.f;
  }
  #pragma unroll
  for(int i=0;i<N1;++i){
    float xf[8];
    #pragma unroll
    for(int pr=0;pr<4;++pr){
      unsigned u = x1p[O1+i][pr];
      xf[2*pr]   = __uint_as_float(u << 16);
      xf[2*pr+1] = __uint_as_float(u & 0xffff0000u);
    }
    #pragma unroll
    for(int k=0;k<NO;++k){
      #pragma unroll
      for(int e=0;e<8;++e) a8[k][e] += cc[k][i]*xf[e];
    }
  }
  #pragma unroll
  for(int k=0;k<NO;++k){
    uint4 o;
    o.x = pkbf(a8[k][0], a8[k][1]);
    o.y = pkbf(a8[k][2], a8[k][3]);
    o.z = pkbf(a8[k][4], a8[k][5]);
    o.w = pkbf(a8[k][6], a8[k][7]);
    sxxU4[(k*16 + z)*16 + ((ug ^ z) & 15)] = o;
  }
}

// ---------------- GEMM pieces ----------------------------------------------
// B-fragments first (all sWT reads for this path, wave-own rows only), so the
// next path's async stage can be issued before the MFMA/phaseA tail.
DEVFN void path_gemm_pre(const uint4* sWTU4, short8 bfr[2][4], int lane, int wv){
  const int m = lane & 15, q = lane >> 4;
  #pragma unroll
  for(int ks=0; ks<4; ++ks){
    const int gp = ((ks*4 + q) ^ m) & 15;     // swizzled group position
    #pragma unroll
    for(int ct=0; ct<2; ++ct){
      const int w = (wv*2 + ct)*16 + m;       // row in wave-own [wv*32,wv*32+32)
      bfr[ct][ks] = bc<short8>(sWTU4[w*16 + gp]);
    }
  }
}

template<int INS>
DEVFN void path_gemm_mfma(const uint4* sxxU4, const short8 bfr[2][4],
                          f32x4 (*acc)[2], int lane)
{
  constexpr int NO = 2*I_LO[INS]+1;
  const int m = lane & 15, q = lane >> 4;
  __builtin_amdgcn_s_setprio(1);
  #pragma unroll
  for(int ks=0; ks<4; ++ks){
    const int gp = ((ks*4 + q) ^ m) & 15;
    short8 a[NO];
    #pragma unroll
    for(int k=0;k<NO;++k)
      a[k] = bc<short8>(sxxU4[(k*16 + m)*16 + gp]);
    #pragma unroll
    for(int ct=0; ct<2; ++ct){
      #pragma unroll
      for(int k=0;k<NO;++k)
        acc[k][ct] = __builtin_amdgcn_mfma_f32_16x16x32_bf16(a[k], bfr[ct][ks], acc[k][ct], 0,0,0);
    }
  }
  __builtin_amdgcn_s_setprio(0);
}

// wave-private async staging: wave wv stages ONLY its own 32 w-rows (8 KB =
// 512 uint4 = 8 instrs x 64 lanes x 16B). LDS dst per instr is wave-uniform
// base + lane*16 (linear), as global_load_lds requires. Because no other wave
// ever touches these rows, sWT needs NO barrier — only this wave's vmcnt.
DEVFN void stage_wt_wave(const uint4* __restrict__ wsrc, uint4* sWT,
                         int wv, int lane){
  typedef __attribute__((address_space(1))) const void gvoid;
  typedef __attribute__((address_space(3))) void lvoid;
  #pragma unroll
  for(int r=0;r<8;++r){
    const int off = wv*512 + r*64 + lane;
    gvoid* gp = (gvoid*)(wsrc + off);
    lvoid* lp = (lvoid*)(sWT  + off);
    __builtin_amdgcn_global_load_lds(gp, lp, 16, 0, 0);
  }
}

// ---------------- epilogue per lo-group -------------------------------------
template<int LO, int NO>
DEVFN void write_out(float* __restrict__ out, long zbase,
                     const f32x4 (*acc)[2], int lane, int wv)
{
  constexpr int OO = LOFF[LO];
  const int col = lane & 15, q = lane >> 4;
  #pragma unroll
  for(int k=0;k<NO;++k){
    #pragma unroll
    for(int ct=0;ct<2;++ct){
      #pragma unroll
      for(int r=0;r<4;++r)
        out[(zbase + q*4 + r)*1152 + (OO+k)*128 + (wv*2 + ct)*16 + col] = acc[k][ct][r];
    }
  }
}

template<int NK>
DEVFN void zacc(f32x4 (*a)[2]){
  #pragma unroll
  for(int k=0;k<NK;++k){
    #pragma unroll
    for(int c=0;c<2;++c){ f32x4 zz = {0.f,0.f,0.f,0.f}; a[k][c] = zz; }
  }
}

// ---------------- main kernel -----------------------------------------------
// Pipelined epochs, ONE barrier per path:
//   epoch k: [wait own vmcnt -> sWT(k) ready] [B-frags -> regs] [lgkm0]
//            [issue async stage sWT(k+1), wave-own rows]
//            [MFMA path k from sxx[k&1]] || [phaseA path k+1 -> sxx[(k+1)&1]]
//            [lgkm0 ; raw s_barrier]   <- NO vmcnt drain: prefetch stays in flight
// sxx double-buffered (2x20480B) + sWT single (32768B) = 73,728 B -> 2 blk/CU.
// launch_bounds(256,2): 256-reg cap, no spills (R2 lesson: (256,3) spilled,
// +235MB scratch traffic, dur 254->311).
__global__ __launch_bounds__(256, 2)
void tp_kernel(const float* __restrict__ x1, const float* __restrict__ x2,
               const unsigned short* __restrict__ wsb, float* __restrict__ out,
               TPParams P)
{
  __shared__ uint4 sxx[2][5*16*16];  // 2 x 20480 B  xx_p dbuf, bf16 swizzled
  __shared__ uint4 sWTU4[2048];      // 32768 B      WT_p, bf16 swizzled

  const int tid = threadIdx.x;
  const long zbase = (long)blockIdx.x * TILE_Z;
  const int z = tid >> 4, ug = tid & 15;       // phase-A mapping
  const int lane = tid & 63, wv = tid >> 6;    // GEMM mapping

  const uint4* wsbU4 = reinterpret_cast<const uint4*>(wsb);

  // prologue: issue path-0 weight stage first (max flight time), then x1/x2
  stage_wt_wave(wsbU4 + 0*2048, sWTU4, wv, lane);

  unsigned x1p[9][4];
  float x2r[9];
  {
    const float* xsrc = x1 + (zbase + z)*1152 + ug*8;
    #pragma unroll
    for(int i=0;i<9;++i){
      float4 a = *reinterpret_cast<const float4*>(xsrc + i*128);
      float4 b = *reinterpret_cast<const float4*>(xsrc + i*128 + 4);
      x1p[i][0] = pkbf(a.x, a.y); x1p[i][1] = pkbf(a.z, a.w);
      x1p[i][2] = pkbf(b.x, b.y); x1p[i][3] = pkbf(b.z, b.w);
    }
    #pragma unroll
    for(int j=0;j<9;++j) x2r[j] = x2[(zbase + z)*9 + j];
  }

  path_phaseA<0>(P, x1p, x2r, sxx[0], z, ug);
  asm volatile("s_waitcnt lgkmcnt(0)" ::: "memory");  // sxx[0] writes visible
  __builtin_amdgcn_s_barrier();

  // EPOCH(CUR, NXT, ACC, EB): gemm path CUR from sxx[EB]; prefetch+phaseA NXT.
#define EPOCH(CUR, NXT, ACC, EB)                                          \
  {                                                                       \
    asm volatile("s_waitcnt vmcnt(0)" ::: "memory");   /* sWT(CUR) in */  \
    __builtin_amdgcn_sched_barrier(0);                                    \
    short8 bfr[2][4];                                                     \
    path_gemm_pre(sWTU4, bfr, lane, wv);                                  \
    asm volatile("s_waitcnt lgkmcnt(0)" ::: "memory"); /* reads retired */\
    __builtin_amdgcn_sched_barrier(0);                                    \
    stage_wt_wave(wsbU4 + (NXT)*2048, sWTU4, wv, lane);                   \
    path_gemm_mfma<CUR>(sxx[EB], bfr, ACC, lane);                         \
    path_phaseA<NXT>(P, x1p, x2r, sxx[(EB)^1], z, ug);                    \
    asm volatile("s_waitcnt lgkmcnt(0)" ::: "memory"); /* ds_writes out */\
    __builtin_amdgcn_s_barrier();                                         \
  }

#define EPOCH_LAST(CUR, ACC, EB)                                          \
  {                                                                       \
    asm volatile("s_waitcnt vmcnt(0)" ::: "memory");                      \
    __builtin_amdgcn_sched_barrier(0);                                    \
    short8 bfr[2][4];                                                     \
    path_gemm_pre(sWTU4, bfr, lane, wv);                                  \
    path_gemm_mfma<CUR>(sxx[EB], bfr, ACC, lane);                         \
  }

  // path order: grouped by lo so each group's accumulator has a short life.
  // P = [0,4,12 | 1,3,5,7,10,13 | 2,6,8,9,11,14]
  f32x4 a0[1][2], a1[3][2], a2[5][2];

  zacc<1>(a0);
  EPOCH(0,  4,  a0, 0)
  EPOCH(4,  12, a0, 1)
  EPOCH(12, 1,  a0, 0)
  write_out<0,1>(out, zbase, a0, lane, wv);

  zacc<3>(a1);
  EPOCH(1,  3,  a1, 1)
  EPOCH(3,  5,  a1, 0)
  EPOCH(5,  7,  a1, 1)
  EPOCH(7,  10, a1, 0)
  EPOCH(10, 13, a1, 1)
  EPOCH(13, 2,  a1, 0)
  write_out<1,3>(out, zbase, a1, lane, wv);

  zacc<5>(a2);
  EPOCH(2,  6,  a2, 1)
  EPOCH(6,  8,  a2, 0)
  EPOCH(8,  9,  a2, 1)
  EPOCH(9,  11, a2, 0)
  EPOCH(11, 14, a2, 1)
  EPOCH_LAST(14, a2, 0)
  write_out<2,5>(out, zbase, a2, lane, wv);

#undef EPOCH
#undef EPOCH_LAST
}

extern "C" void kernel_launch(void* const* d_in, const int* in_sizes, int n_in,
                              void* d_out, int out_size, void* d_ws, size_t ws_size,
                              hipStream_t stream)
{
  (void)in_sizes; (void)n_in; (void)out_size; (void)ws_size;
  const float* x1 = (const float*)d_in[0];
  const float* x2 = (const float*)d_in[1];
  const float* wt = (const float*)d_in[2];
  float* out = (float*)d_out;
  unsigned short* wsb = (unsigned short*)d_ws;   // 491,520 B used

  // host-side wigner-3j tables are deterministic — compute once per process
  static TPParams P;
  static AlphaArg A;
  static bool inited = false;
  if(!inited){ fill_params(P, A); inited = true; }

  prep_kernel<<<dim3(960), dim3(256), 0, stream>>>(wt, wsb, A);
  tp_kernel<<<dim3(NBLOCK), dim3(256), 0, stream>>>(x1, x2, wsb, out, P);
}

// Round 4
// 455.599 us; speedup vs baseline: 2.6459x; 2.6459x over previous
//
#include <hip/hip_runtime.h>
#include <cmath>
#include <complex>
#include <vector>
#include <algorithm>

#define DEVFN __device__ __forceinline__

typedef short short8 __attribute__((ext_vector_type(8)));
typedef float f32x4  __attribute__((ext_vector_type(4)));

namespace {

constexpr int NNODE  = 50000;
constexpr int TILE_Z = 16;
constexpr int NBLOCK = NNODE / TILE_Z;   // 3125, exact
static_assert(NBLOCK * TILE_Z == NNODE, "tile");

// INSTR = [(0,0,0),(0,1,1),(0,2,2),(1,0,1),(1,1,0),(1,1,1),(1,1,2),(1,2,1),
//          (1,2,2),(2,0,2),(2,1,1),(2,1,2),(2,2,0),(2,2,1),(2,2,2)]
constexpr int I_L1[15] = {0,0,0,1,1,1,1,1,1,2,2,2,2,2,2};
constexpr int I_L2[15] = {0,1,2,0,1,1,1,2,2,0,1,1,2,2,2};
constexpr int I_LO[15] = {0,1,2,1,0,1,2,1,2,2,1,2,0,1,2};
// flattened w3j offsets; sizes (2l1+1)(2l2+1)(2lo+1) -> total 615
constexpr int W3OFF[15] = {0,1,10,35,44,53,80,125,170,245,270,315,390,415,490};
constexpr int LOFF[3] = {0,1,4};     // basis-dim offset of each l block

struct TPParams { float w3j[615]; };
struct AlphaArg { float a[15]; };

// ---------------- host: e3nn-convention wigner 3j (proven) ------------------
double ffact(int n){ double r=1.0; for(int i=2;i<=n;++i) r*=i; return r; }

double su2cg(int j1,int m1,int j2,int m2,int j3,int m3){
  if(m3 != m1+m2) return 0.0;
  int vmin = std::max(std::max(-j1+j2+m3, -j1+m1), 0);
  int vmax = std::min(std::min(j2+j3+m1, j3-j1+j2), j3+m3);
  double C = std::sqrt((2.0*j3+1.0)*ffact(j3+j1-j2)*ffact(j3-j1+j2)*ffact(j1+j2-j3)
             /ffact(j1+j2+j3+1)
             *ffact(j3+m3)*ffact(j3-m3)
             /(ffact(j1-m1)*ffact(j1+m1)*ffact(j2-m2)*ffact(j2+m2)));
  double S = 0.0;
  for(int v=vmin; v<=vmax; ++v){
    double t = ffact(j2+j3+m1-v)*ffact(j1-m1+v)
             /(ffact(v)*ffact(j3-j1+j2-v)*ffact(j3+m3-v)*ffact(v+j1-j2-m3));
    S += ((v+j2+m2)&1) ? -t : t;
  }
  return C*S;
}

void cbasis(int l, std::complex<double>* q){
  int n = 2*l+1;
  for(int i=0;i<n*n;++i) q[i] = std::complex<double>(0.0,0.0);
  const double is2 = 1.0/std::sqrt(2.0);
  for(int m=-l; m<0; ++m){
    q[(l+m)*n + (l-m)] = std::complex<double>(is2, 0.0);
    q[(l+m)*n + (l+m)] = std::complex<double>(0.0, -is2);
  }
  q[l*n+l] = std::complex<double>(1.0, 0.0);
  for(int m=1; m<=l; ++m){
    double s = (m&1) ? -1.0 : 1.0;
    q[(l+m)*n + (l+m)] = std::complex<double>(s*is2, 0.0);
    q[(l+m)*n + (l-m)] = std::complex<double>(0.0, s*is2);
  }
  std::complex<double> ph;
  switch(l&3){ case 0: ph = std::complex<double>(1,0);  break;
               case 1: ph = std::complex<double>(0,-1); break;
               case 2: ph = std::complex<double>(-1,0); break;
               default: ph = std::complex<double>(0,1);  break; }
  for(int i=0;i<n*n;++i) q[i] *= ph;
}

void wigner3j_tab(int l1,int l2,int l3, float* dst){
  int n1=2*l1+1, n2=2*l2+1, n3=2*l3+1;
  std::vector<double> C(n1*n2*n3);
  for(int i=0;i<n1;++i) for(int k=0;k<n2;++k) for(int n=0;n<n3;++n)
    C[(i*n2+k)*n3+n] = su2cg(l1,i-l1, l2,k-l2, l3,n-l3);
  std::vector<std::complex<double>> Q1(n1*n1), Q2(n2*n2), Q3(n3*n3);
  cbasis(l1,Q1.data()); cbasis(l2,Q2.data()); cbasis(l3,Q3.data());
  std::vector<double> R(n1*n2*n3, 0.0);
  for(int j=0;j<n1;++j) for(int l=0;l<n2;++l) for(int m=0;m<n3;++m){
    std::complex<double> s(0,0);
    for(int i=0;i<n1;++i) for(int k=0;k<n2;++k) for(int n=0;n<n3;++n)
      s += Q1[i*n1+j]*Q2[k*n2+l]*std::conj(Q3[n*n3+m])*C[(i*n2+k)*n3+n];
    R[(j*n2+l)*n3+m] = s.real();
  }
  double nrm=0; for(double v:R) nrm += v*v; nrm = std::sqrt(nrm);
  for(int t=0;t<n1*n2*n3;++t) dst[t] = (float)(R[t]/nrm);
}

void fill_params(TPParams& P, AlphaArg& A){
  for(int ins=0; ins<15; ++ins)
    wigner3j_tab(I_L1[ins], I_L2[ins], I_LO[ins], P.w3j + W3OFF[ins]);
  int cnt[3] = {0,0,0};
  for(int ins=0; ins<15; ++ins) cnt[I_LO[ins]]++;      // {3,6,6}
  for(int ins=0; ins<15; ++ins){
    int lo = I_LO[ins];
    A.a[ins] = (float)std::sqrt((2.0*lo+1.0)/(128.0*cnt[lo]));
  }
}

} // namespace

// ---------------- device helpers -------------------------------------------
DEVFN unsigned f2bf(float f){                       // fp32 -> bf16 bits (RNE)
  unsigned u = __float_as_uint(f);
  return (u + 0x7fffu + ((u>>16)&1u)) >> 16;
}
DEVFN unsigned pkbf(float a, float b){ return f2bf(a) | (f2bf(b)<<16); }

// packed bf16 pair via HW cvt (1 inst vs ~7): dst.lo=bf16(a), dst.hi=bf16(b)
DEVFN unsigned cvtpk(float a, float b){
  unsigned r;
  asm("v_cvt_pk_bf16_f32 %0, %1, %2" : "=v"(r) : "v"(a), "v"(b));
  return r;
}

template<typename T, typename F>
DEVFN T bc(F f){ static_assert(sizeof(T)==sizeof(F), "size"); T t; __builtin_memcpy(&t,&f,sizeof(T)); return t; }

// ---------------- prep: weights -> bf16 B-fragments, alpha folded -----------
// Output layout (uint4 units): ws2[p][wb][ks][lane], wb=0..7 (w-block),
// ks=0..3 (K step), lane=0..63. Lane l (m=l&15,q=l>>4) holds 8 bf16:
//   weight[u = (ks*4+q)*8 + e][wcol = wb*16 + m] * alpha_p , e=0..7
// i.e. exactly the MFMA B-fragment for (wb,ks); kernel loads are 1KB
// fully-coalesced global_load_dwordx4 per (ct,ks). Total 491,520 B.
__global__ __launch_bounds__(256)
void prep_kernel(const float* __restrict__ w, unsigned short* __restrict__ ws,
                 AlphaArg al)
{
  int v = blockIdx.x*256 + threadIdx.x;          // < 15*2048 = 30720
  int p = v >> 11, r = v & 2047;
  int ks = (r>>6)&3, ln = r&63;
  int q = ln>>4, m = ln&15;
  int wcol = (r>>8)*16 + m;
  float a = al.a[p];
  const float* src = w + p*16384 + wcol;
  uint4 o;
  unsigned tmp[4];
  #pragma unroll
  for(int pr=0; pr<4; ++pr){
    int u0 = (ks*4+q)*8 + pr*2;
    float lo = src[u0*128]     * a;
    float hi = src[(u0+1)*128] * a;
    tmp[pr] = pkbf(lo, hi);
  }
  o.x = tmp[0]; o.y = tmp[1]; o.z = tmp[2]; o.w = tmp[3];
  reinterpret_cast<uint4*>(ws)[v] = o;
}

// ---------------- phase A: xx_p[k][z][u] (bf16, swizzled) -------------------
template<int INS>
DEVFN void path_phaseA(const TPParams& P, const unsigned x1p[9][4],
                       const float x2r[9], uint4* sxxU4, int z, int ug)
{
  constexpr int L1 = I_L1[INS], L2 = I_L2[INS], LO = I_LO[INS];
  constexpr int N1 = 2*L1+1, N2 = 2*L2+1, NO = 2*LO+1;
  constexpr int O1 = LOFF[L1], O2 = LOFF[L2], W3 = W3OFF[INS];

  float cc[NO][N1];
  #pragma unroll
  for(int k=0;k<NO;++k){
    #pragma unroll
    for(int i=0;i<N1;++i){
      float s = 0.f;
      #pragma unroll
      for(int j=0;j<N2;++j)
        s += P.w3j[W3 + (i*N2+j)*NO + k] * x2r[O2 + j];
      cc[k][i] = s;
    }
  }
  float a8[NO][8];
  #pragma unroll
  for(int k=0;k<NO;++k){
    #pragma unroll
    for(int e=0;e<8;++e) a8[k][e]=0.f;
  }
  #pragma unroll
  for(int i=0;i<N1;++i){
    float xf[8];
    #pragma unroll
    for(int pr=0;pr<4;++pr){
      unsigned u = x1p[O1+i][pr];
      xf[2*pr]   = __uint_as_float(u << 16);
      xf[2*pr+1] = __uint_as_float(u & 0xffff0000u);
    }
    #pragma unroll
    for(int k=0;k<NO;++k){
      #pragma unroll
      for(int e=0;e<8;++e) a8[k][e] += cc[k][i]*xf[e];
    }
  }
  #pragma unroll
  for(int k=0;k<NO;++k){
    uint4 o;
    o.x = cvtpk(a8[k][0], a8[k][1]);
    o.y = cvtpk(a8[k][2], a8[k][3]);
    o.z = cvtpk(a8[k][4], a8[k][5]);
    o.w = cvtpk(a8[k][6], a8[k][7]);
    sxxU4[(k*16 + z)*16 + ((ug ^ z) & 15)] = o;
  }
}

// ---------------- B-fragment load (global -> regs, L2-resident) -------------
DEVFN void loadB(const uint4* __restrict__ src, short8 (&bfr)[2][4],
                 int lane, int wv){
  #pragma unroll
  for(int ct=0; ct<2; ++ct){
    #pragma unroll
    for(int ks=0; ks<4; ++ks)
      bfr[ct][ks] = bc<short8>(src[(wv*2+ct)*256 + ks*64 + lane]);
  }
}

// ---------------- GEMM phase: acc[k][ct] += xx_p . B ------------------------
template<int INS>
DEVFN void path_gemm(const uint4* sxxU4, const short8 (&bfr)[2][4],
                     f32x4 (*acc)[2], int lane)
{
  constexpr int NO = 2*I_LO[INS]+1;
  const int m = lane & 15, q = lane >> 4;
  #pragma unroll
  for(int ks=0; ks<4; ++ks){
    const int gp = ((ks*4 + q) ^ m) & 15;     // swizzled group position
    short8 a[NO];
    #pragma unroll
    for(int k=0;k<NO;++k)
      a[k] = bc<short8>(sxxU4[(k*16 + m)*16 + gp]);
    #pragma unroll
    for(int ct=0; ct<2; ++ct){
      #pragma unroll
      for(int k=0;k<NO;++k)
        acc[k][ct] = __builtin_amdgcn_mfma_f32_16x16x32_bf16(a[k], bfr[ct][ks], acc[k][ct], 0,0,0);
    }
  }
}

// ---------------- epilogue per lo-group -------------------------------------
template<int LO, int NO>
DEVFN void write_out(float* __restrict__ out, long zbase,
                     const f32x4 (*acc)[2], int lane, int wv)
{
  constexpr int OO = LOFF[LO];
  const int col = lane & 15, q = lane >> 4;
  #pragma unroll
  for(int k=0;k<NO;++k){
    #pragma unroll
    for(int ct=0;ct<2;++ct){
      #pragma unroll
      for(int r=0;r<4;++r)
        out[(zbase + q*4 + r)*1152 + (OO+k)*128 + (wv*2 + ct)*16 + col] = acc[k][ct][r];
    }
  }
}

template<int NK>
DEVFN void zacc(f32x4 (*a)[2]){
  #pragma unroll
  for(int k=0;k<NK;++k){
    #pragma unroll
    for(int c=0;c<2;++c){ f32x4 zz = {0.f,0.f,0.f,0.f}; a[k][c] = zz; }
  }
}

// ---------------- main kernel -----------------------------------------------
// R0's proven 2-barrier-per-path structure (phaseA / GEMM register lifetimes
// DISJOINT -> no spills; R2/R3 lesson), with:
//  * B operand in registers (2x32-VGPR double buffer, loads issued one path
//    ahead from the L2-resident fragment table) -> no sWT LDS, no staging
//    vmcnt drain at barriers, -8 LDS reads per wave*path
//  * raw s_barrier + lgkmcnt(0) only (B prefetch stays in flight)
//  * LDS = sxx only, 20480 B
__global__ __launch_bounds__(256, 2)
void tp_kernel(const float* __restrict__ x1, const float* __restrict__ x2,
               const unsigned short* __restrict__ wsb, float* __restrict__ out,
               TPParams P)
{
  __shared__ uint4 sxx[5*16*16];     // 20480 B  xx_p, bf16 swizzled

  const int tid = threadIdx.x;
  const long zbase = (long)blockIdx.x * TILE_Z;
  const int z = tid >> 4, ug = tid & 15;       // phase-A mapping
  const int lane = tid & 63, wv = tid >> 6;    // GEMM mapping

  const uint4* ws2U4 = reinterpret_cast<const uint4*>(wsb);

  short8 B0[2][4], B1[2][4];

  // prologue: issue path-0 B loads first (max flight), then x1/x2, phaseA(0)
  loadB(ws2U4 + 0*2048, B0, lane, wv);

  unsigned x1p[9][4];
  float x2r[9];
  {
    const float* xsrc = x1 + (zbase + z)*1152 + ug*8;
    #pragma unroll
    for(int i=0;i<9;++i){
      float4 a = *reinterpret_cast<const float4*>(xsrc + i*128);
      float4 b = *reinterpret_cast<const float4*>(xsrc + i*128 + 4);
      x1p[i][0] = cvtpk(a.x, a.y); x1p[i][1] = cvtpk(a.z, a.w);
      x1p[i][2] = cvtpk(b.x, b.y); x1p[i][3] = cvtpk(b.z, b.w);
    }
    #pragma unroll
    for(int j=0;j<9;++j) x2r[j] = x2[(zbase + z)*9 + j];
  }

  path_phaseA<0>(P, x1p, x2r, sxx, z, ug);

  // raw barrier + LDS-only wait: B prefetch (vmcnt) stays in flight
#define BAR_LGKM                                             \
  asm volatile("s_waitcnt lgkmcnt(0)" ::: "memory");         \
  __builtin_amdgcn_s_barrier();

  BAR_LGKM

  // STEP: issue B(NXT) loads, GEMM CUR (B from regs, A from sxx),
  //       barrier, phaseA NXT overwrites sxx, barrier.
#define STEP(CUR, NXT, ACC, BCUR, BNXT)                      \
  loadB(ws2U4 + (NXT)*2048, BNXT, lane, wv);                 \
  path_gemm<CUR>(sxx, BCUR, ACC, lane);                      \
  BAR_LGKM                                                   \
  path_phaseA<NXT>(P, x1p, x2r, sxx, z, ug);                 \
  BAR_LGKM

#define STEP_LAST(CUR, ACC, BCUR)                            \
  path_gemm<CUR>(sxx, BCUR, ACC, lane);

  // path order grouped by lo (acc lifetime short):
  // [0,4,12 | 1,3,5,7,10,13 | 2,6,8,9,11,14]
  f32x4 a0[1][2], a1[3][2], a2[5][2];

  zacc<1>(a0); zacc<3>(a1); zacc<5>(a2);

  STEP(0,  4,  a0, B0, B1)
  STEP(4,  12, a0, B1, B0)
  STEP(12, 1,  a0, B0, B1)
  write_out<0,1>(out, zbase, a0, lane, wv);

  STEP(1,  3,  a1, B1, B0)
  STEP(3,  5,  a1, B0, B1)
  STEP(5,  7,  a1, B1, B0)
  STEP(7,  10, a1, B0, B1)
  STEP(10, 13, a1, B1, B0)
  STEP(13, 2,  a1, B0, B1)
  write_out<1,3>(out, zbase, a1, lane, wv);

  STEP(2,  6,  a2, B1, B0)
  STEP(6,  8,  a2, B0, B1)
  STEP(8,  9,  a2, B1, B0)
  STEP(9,  11, a2, B0, B1)
  STEP(11, 14, a2, B1, B0)
  STEP_LAST(14, a2, B0)
  write_out<2,5>(out, zbase, a2, lane, wv);

#undef STEP
#undef STEP_LAST
#undef BAR_LGKM
}

extern "C" void kernel_launch(void* const* d_in, const int* in_sizes, int n_in,
                              void* d_out, int out_size, void* d_ws, size_t ws_size,
                              hipStream_t stream)
{
  (void)in_sizes; (void)n_in; (void)out_size; (void)ws_size;
  const float* x1 = (const float*)d_in[0];
  const float* x2 = (const float*)d_in[1];
  const float* wt = (const float*)d_in[2];
  float* out = (float*)d_out;
  unsigned short* wsb = (unsigned short*)d_ws;   // 491,520 B used

  // host-side wigner-3j tables are deterministic — compute once per process
  static TPParams P;
  static AlphaArg A;
  static bool inited = false;
  if(!inited){ fill_params(P, A); inited = true; }

  prep_kernel<<<dim3(120), dim3(256), 0, stream>>>(wt, wsb, A);
  tp_kernel<<<dim3(NBLOCK), dim3(256), 0, stream>>>(x1, x2, wsb, out, P);
}